// Round 9
// baseline (324.196 us; speedup 1.0000x reference)
//
#include <hip/hip_runtime.h>

typedef _Float16 f16;
typedef _Float16 f16x4 __attribute__((ext_vector_type(4)));
typedef _Float16 f16x8 __attribute__((ext_vector_type(8)));
typedef float    f32x4 __attribute__((ext_vector_type(4)));

#define H_DIM 1024
#define S_DIM 1024
#define PLANE (1024*1024)
#define MT 128
#define NT 64
#define KT 32
#define AP (MT*KT)        // one A plane in LDS, f16 elems (4096)
#define ABUF (2*AP)       // one A buffer (2 planes), 8192 f16 = 16 KB
#define XOFF (6*PLANE)    // x_f16 after 2 spans * 3 weight planes
#define NBLK 512
#define OUT_LAST 8388607  // 2*4096*1024 - 1: counter slot, overwritten by epilogue

// global -> LDS direct DMA, 16 B/lane; LDS dest = wave-uniform base + lane*16
__device__ __forceinline__ void load_lds16(const f16* g, f16* l) {
    __builtin_amdgcn_global_load_lds(
        (const __attribute__((address_space(1))) void*)g,
        (__attribute__((address_space(3))) void*)l, 16, 0, 0);
}

// K_STEP: R4-VERIFIED two-barrier pipeline step (all-DMA staging; no
// register-dest global loads in the loop — R5/R7 showed those poison the
// pipeline via compiler re-waits). Swizzle R4-verified: conflicts 7.34M -> 0.
#define K_STEP(FB, FA, WCNT, FIN)                                              \
  {                                                                            \
    f16x8 afr0[4], afr1[4], bfrg[6];                                           \
    const f16* Ab = &A_all[rbA];                                               \
    _Pragma("unroll")                                                          \
    for (int mf = 0; mf < 4; ++mf) {                                           \
      int r = (wm + mf * 16 + lrow) * KT + lqs * 8;                            \
      afr0[mf] = *(const f16x8*)&Ab[r];                                        \
      afr1[mf] = *(const f16x8*)&Ab[AP + r];                                   \
    }                                                                          \
    _Pragma("unroll")                                                          \
    for (int j = 0; j < 6; ++j) {                                              \
      int pp = j >> 1, nf = j & 1;                                             \
      bfrg[j] = *(const f16x8*)&B_lds[pp * 2048 + (wn + nf * 16 + lrow) * KT + lqs * 8]; \
    }                                                                          \
    if (!(FIN)) {                                                              \
      __asm__ volatile("s_waitcnt lgkmcnt(0)" ::: "memory");                   \
      __builtin_amdgcn_s_barrier();                                            \
      if (FB) {                                                                \
        _Pragma("unroll")                                                      \
        for (int j = 0; j < 3; ++j) { load_lds16(bq[j], &B_lds[bdst[j]]); bq[j] += KT; } \
      }                                                                        \
      if (FA) {                                                                \
        f16* dst = &A_all[wbA];                                                \
        _Pragma("unroll")                                                      \
        for (int j = 0; j < 4; ++j) { load_lds16(ap[j], dst + adst[j]); ap[j] += KT; } \
      }                                                                        \
    }                                                                          \
    _Pragma("unroll")                                                          \
    for (int mf = 0; mf < 4; ++mf)                                             \
      _Pragma("unroll")                                                        \
      for (int nf = 0; nf < 2; ++nf) {                                         \
        accL[mf][nf] = __builtin_amdgcn_mfma_f32_16x16x32_f16(afr0[mf], bfrg[0*2+nf], accL[mf][nf], 0,0,0); \
        accL[mf][nf] = __builtin_amdgcn_mfma_f32_16x16x32_f16(afr1[mf], bfrg[1*2+nf], accL[mf][nf], 0,0,0); \
        accP[mf][nf] = __builtin_amdgcn_mfma_f32_16x16x32_f16(afr0[mf], bfrg[2*2+nf], accP[mf][nf], 0,0,0); \
        accQ[mf][nf] = __builtin_amdgcn_mfma_f32_16x16x32_f16(afr1[mf], bfrg[2*2+nf], accQ[mf][nf], 0,0,0); \
      }                                                                        \
    if (!(FIN)) {                                                              \
      __asm__ volatile("s_waitcnt vmcnt(" #WCNT ")" ::: "memory");             \
      __builtin_amdgcn_s_barrier();                                            \
      rbA = (rbA == 2 * ABUF) ? 0 : rbA + ABUF;                                \
      wbA = (wbA == 2 * ABUF) ? 0 : wbA + ABUF;                                \
    }                                                                          \
  }

// ---- fused_all: prep + grid-barrier + 2x span tiles in ONE launch ----
// Rationale (R1/R4/R8): three prep restructurings changed total by ~0 =>
// the ~150us non-span gap is dispatch/serialization-bound, not prep-quality-
// bound. Fuse everything; the only remaining dispatch is this kernel + a
// 4-byte memset for the barrier counter.
// Grid = 512 = exact 2-blocks/CU capacity (60KB LDS, launch_bounds(256,2))
// per the guide's k x 256 co-residency rule. Barrier: device-scope fences
// (__threadfence = L2 wb/inv on CDNA) around an atomic counter (G16-safe).
// Counter lives in out[OUT_LAST]: zeroed by in-graph memset, consumed only
// inside the barrier, overwritten with the real output by the epilogue.
__global__ __launch_bounds__(256, 2) void fused_all(
    const float* __restrict__ x,
    const int* __restrict__ idxP, const int* __restrict__ idxH,
    const float* __restrict__ Wp1, const float* __restrict__ Wp2,
    const float* __restrict__ Wp3, const float* __restrict__ Wp4,
    const float* __restrict__ Wh1, const float* __restrict__ Wh2,
    const float* __restrict__ Wh3, const float* __restrict__ Wh4,
    const float* __restrict__ bp1, const float* __restrict__ bp2, const float* __restrict__ bp4,
    const float* __restrict__ bh1, const float* __restrict__ bh2, const float* __restrict__ bh4,
    f16* __restrict__ ws, unsigned* __restrict__ cnt,
    float* __restrict__ out)
{
    const int p = blockIdx.x;
    const int t = threadIdx.x;

    // ---------------- phase A: prep slice (1/512 of everything) ----------
    // x fp32->fp16: 4,194,304 f32x4 chunks; 8192/block, 32/thread (8-deep ILP)
    {
        const size_t cb = (size_t)p * 8192;
        for (int g = 0; g < 4; ++g) {
#pragma unroll
            for (int k = 0; k < 8; ++k) {
                const size_t i = (cb + (size_t)(g * 8 + k) * 256 + t) * 4;
                f32x4 v = *(const f32x4*)(x + i);
                f16x4 h;
#pragma unroll
                for (int j = 0; j < 4; ++j) h[j] = (f16)v[j];
                *(f16x4*)(ws + XOFF + i) = h;
            }
        }
        // weight fold: 524,288 chunks (2 spans x 1M floats); 1024/block
#pragma unroll
        for (int it = 0; it < 4; ++it) {
            const int c  = p * 1024 + it * 256 + t;
            const int sp = c >> 18;
            const size_t i = (size_t)(c & 262143) * 4;
            const float* W1 = sp ? Wh1 : Wp1;
            const float* W2 = sp ? Wh2 : Wp2;
            const float* W3 = sp ? Wh3 : Wp3;
            const float* W4 = sp ? Wh4 : Wp4;
            f16* base = ws + (size_t)sp * 3 * PLANE;

            f32x4 w1 = *(const f32x4*)(W1 + i);
            f32x4 w2 = *(const f32x4*)(W2 + i);
            f32x4 w3 = *(const f32x4*)(W3 + i);
            f32x4 w4 = *(const f32x4*)(W4 + i);

            f16x4 wa, wb2, wc;
#pragma unroll
            for (int j = 0; j < 4; ++j) {
                wa[j]  = (f16)(w1[j] + w3[j]);
                wb2[j] = (f16)(w2[j] - w3[j]);
                wc[j]  = (f16)w4[j];
            }
            *(f16x4*)(base + 0*PLANE + i) = wa;
            *(f16x4*)(base + 1*PLANE + i) = wb2;
            *(f16x4*)(base + 2*PLANE + i) = wc;
        }
    }

    // ---------------- grid barrier (device-scope, cross-XCD safe) --------
    __syncthreads();                 // block's ws stores drained (vmcnt(0) at barrier)
    if (t == 0) {
        __threadfence();             // release: L2 writeback -> L3/HBM
        unsigned v = atomicAdd(cnt, 1u) + 1u;
        while (v < NBLK) {
            __builtin_amdgcn_s_sleep(2);
            v = atomicAdd(cnt, 0u); // device-scope RMW read (sees remote XCDs)
        }
    }
    __syncthreads();
    __threadfence();                 // acquire: invalidate -> fresh ws reads

    // ---------------- phase B: two span tiles ---------------------------
    // XCD remap: blocks p = g, g+64, ..., g+448 (same XCD under %8 round-
    // robin) form logical group g = (mtile,span); members are the 8 ntile-
    // pairs -> A rows L2-shared within one XCD. Bijective on [0,512).
    const int L     = ((p & 63) << 3) | (p >> 6);
    const int nt0   = (L & 7) * 2;          // this block's 2 ntiles
    const int mtile = (L >> 3) & 31;
    const int span  = L >> 8;

    const int* idx   = span ? idxH : idxP;
    const f16* wbase = ws + (size_t)span * 3 * PLANE;
    const f16* xh    = ws + XOFF;
    const float* b1 = span ? bh1 : bp1;
    const float* b2 = span ? bh2 : bp2;
    const float* b4 = span ? bh4 : bp4;
    float* obase = out + (size_t)span * 4096 * H_DIM;

    __shared__ __align__(16) f16 A_all[3 * ABUF];    // 48 KB
    __shared__ __align__(16) f16 B_lds[3 * NT * KT]; // 12 KB

    // rowoff staged once via LDS (aliased on A_all), then held in registers
    int* rowoff = (int*)A_all;
    {
        int side = t >> 7, m = t & 127;
        int bk = mtile * MT + m;
        int b  = bk >> 8, kk = bk & 255;
        rowoff[side * 128 + m] = (b * S_DIM + idx[b * 512 + side * 256 + kk]) * H_DIM;
    }
    __syncthreads();

    const int wid  = t >> 6;
    const int lane = t & 63;
    const int wm   = (wid & 1) * 64;
    const int wn   = (wid >> 1) * 32;
    const int lrow = lane & 15;
    const int lq   = lane >> 4;
    const int lqs  = lq ^ ((lrow >> 1) & 3);
    const int schunk = (lane & 3) ^ ((lane >> 3) & 3);

    // A DMA base pointers: ntile-independent -> computed ONCE, reset per tile
    const f16* apb[4]; int adst[4];
#pragma unroll
    for (int j = 0; j < 4; ++j) {
        int o = wid * 4 + j;
        int pl = o >> 3, g = o & 7;
        int r = g * 16 + (lane >> 2);
        apb[j]  = xh + rowoff[pl * 128 + r] + schunk * 8;
        adst[j] = pl * AP + g * 16 * KT;
    }

    for (int ti = 0; ti < 2; ++ti) {
        const int ntile = nt0 + ti;
        __syncthreads();   // rowoff reads done (ti=0) / prior tile's LDS reads done (ti=1)

        // B DMA tasks for this ntile
        const f16* bq[3]; int bdst[3];
#pragma unroll
        for (int j = 0; j < 3; ++j) {
            int o = wid * 3 + j;
            int pl = o >> 2, g = o & 3;
            int grow = ntile * NT + g * 16 + (lane >> 2);
            bq[j]   = wbase + (size_t)pl * PLANE + (size_t)grow * H_DIM + schunk * 8;
            bdst[j] = pl * 2048 + g * 16 * KT;
        }
        const f16* ap[4];
#pragma unroll
        for (int j = 0; j < 4; ++j) ap[j] = apb[j];

        f32x4 accL[4][2], accP[4][2], accQ[4][2];
        {
            f32x4 z = {0.f, 0.f, 0.f, 0.f};
#pragma unroll
            for (int mf = 0; mf < 4; ++mf)
#pragma unroll
                for (int nf = 0; nf < 2; ++nf) { accL[mf][nf] = z; accP[mf][nf] = z; accQ[mf][nf] = z; }
        }

        // prologue: A(0), B(0), A(1); vmcnt(4) keeps A(1) in flight
        // (in-order retirement: any older epilogue stores drain first)
#pragma unroll
        for (int j = 0; j < 4; ++j) { load_lds16(ap[j], &A_all[0 * ABUF + adst[j]]); ap[j] += KT; }
#pragma unroll
        for (int j = 0; j < 3; ++j) { load_lds16(bq[j], &B_lds[bdst[j]]); bq[j] += KT; }
#pragma unroll
        for (int j = 0; j < 4; ++j) { load_lds16(ap[j], &A_all[1 * ABUF + adst[j]]); ap[j] += KT; }
        __asm__ volatile("s_waitcnt vmcnt(4)" ::: "memory");
        __builtin_amdgcn_s_barrier();

        int rbA = 0;
        int wbA = 2 * ABUF;

        for (int ks = 0; ks < 30; ++ks) {
            K_STEP(1, 1, 4, 0);
        }
        K_STEP(1, 0, 0, 0);   // ks=30: fill B(31), no A(32), drain all
        K_STEP(0, 0, 0, 1);   // ks=31: compute only

        // epilogue: span = L + b1 + b2 + (P+b4)*(Q+b4); out = tanh(span)
        // C/D layout (m89-verified): col = lane&15, row = (lane>>4)*4 + i
#pragma unroll
        for (int mf = 0; mf < 4; ++mf)
#pragma unroll
            for (int nf = 0; nf < 2; ++nf) {
                int col = ntile * NT + wn + nf * 16 + lrow;
                float bb12 = b1[col] + b2[col];
                float bb4  = b4[col];
                int row0 = mtile * MT + wm + mf * 16 + lq * 4;
#pragma unroll
                for (int i = 0; i < 4; ++i) {
                    float v = accL[mf][nf][i] + bb12
                            + (accP[mf][nf][i] + bb4) * (accQ[mf][nf][i] + bb4);
                    obase[(size_t)(row0 + i) * H_DIM + col] = tanhf(v);
                }
            }
    }
}

extern "C" void kernel_launch(void* const* d_in, const int* in_sizes, int n_in,
                              void* d_out, int out_size, void* d_ws, size_t ws_size,
                              hipStream_t stream) {
    (void)in_sizes; (void)n_in; (void)out_size; (void)ws_size;
    const float* x    = (const float*)d_in[0];
    const int*   idxP = (const int*)d_in[1];
    const int*   idxH = (const int*)d_in[2];
    const float* Wp1 = (const float*)d_in[3];  const float* bp1 = (const float*)d_in[4];
    const float* Wp2 = (const float*)d_in[5];  const float* bp2 = (const float*)d_in[6];
    const float* Wp3 = (const float*)d_in[7];
    const float* Wp4 = (const float*)d_in[9];  const float* bp4 = (const float*)d_in[10];
    const float* Wh1 = (const float*)d_in[11]; const float* bh1 = (const float*)d_in[12];
    const float* Wh2 = (const float*)d_in[13]; const float* bh2 = (const float*)d_in[14];
    const float* Wh3 = (const float*)d_in[15];
    const float* Wh4 = (const float*)d_in[17]; const float* bh4 = (const float*)d_in[18];
    float* out = (float*)d_out;
    f16*   ws  = (f16*)d_ws;   // weights 12 MB + x_f16 32 MB = 44 MB
    unsigned* cnt = (unsigned*)out + OUT_LAST;   // barrier counter slot

    hipMemsetAsync((void*)cnt, 0, 4, stream);    // zero counter (in-graph)
    fused_all<<<NBLK, 256, 0, stream>>>(x, idxP, idxH,
                                        Wp1, Wp2, Wp3, Wp4,
                                        Wh1, Wh2, Wh3, Wh4,
                                        bp1, bp2, bp4, bh1, bh2, bh4,
                                        ws, cnt, out);
}